// Round 9
// baseline (141.282 us; speedup 1.0000x reference)
//
#include <hip/hip_runtime.h>
#include <hip/hip_bf16.h>

// Conv2dWithLoRA: out = conv3x3(x, W_eff) + b, where W_eff = W + 2.0 * B@A.
// LoRA folded into weights -> single implicit-GEMM conv, bf16 MFMA, fp32 accum.
// M = 16*64*64 = 65536 pixels, N = 256 outs, K = 1152 = 18 K-tiles of 64.
// R3..R9: FIVE structures all at 29-32% MfmaUtil (~50us). None was the proven
//   m201 skeleton; all were ablations around it. m196/m230: coarse phase-split
//   or counted-vmcnt alone is null; the lever is the per-phase fine interleave.
// R10/R11: faithful m201 8-phase port (R11 = compile fix: PHASE declares a
//   local WC so MF's token binds; tail passes wA/wB directly):
//   - 256pix x 256o, 512 thr, 8 waves (wm=pix-half, wn=o-quarter), per-wave
//     128pix x 64o, acc[8][4] (128 acc regs).
//   - K-tile=64. Pixels: LDS 4 slots x 32KB (stage kt+2 overwrites slot
//     (kt-2)&3, >=2 barriers stale -> race-free). Weights: VGPR ping-pong
//     (R8-verified global->reg path, fragment-contiguous layout).
//   - per K-tile: 4 phases {4 ds_read ∥ 1 quarter-stage; SBAR; prio1 8 MFMA;
//     4 ds_read in drain shadow; prio1 8 MFMA} + ONE vmcnt(4) (counted: WL
//     retired, stages stay in flight - never drains mid-loop) + ONE SBAR.
//   - R3-verified 0-conflict swizzle (64-elem rows): chunk ^= row&7, inverse
//     pre-applied on per-lane GLOBAL address, LDS dest linear (rule #21).

#define CIN   128
#define COUT  256
#define NBAT  16
#define HPAD  66
#define WPAD  66

typedef __bf16 bf16x8 __attribute__((ext_vector_type(8)));
typedef float f32x4 __attribute__((ext_vector_type(4)));

#define XPAD_ELEMS ((size_t)NBAT * HPAD * WPAD * CIN)   // 8,921,088
#define XPAD_BYTES (XPAD_ELEMS * 2)                      // 17,842,176
#define WT_ELEMS   ((size_t)9 * COUT * CIN)              // 294,912
#define WS_NEED    (XPAD_BYTES + WT_ELEMS * 2)

typedef __attribute__((address_space(1))) void gvoid;
typedef __attribute__((address_space(3))) void lvoid;

__device__ __forceinline__ void load_lds16(const void* g, void* l) {
    // async global->LDS, 16B per lane; LDS dest = wave-uniform base + lane*16
    __builtin_amdgcn_global_load_lds((gvoid*)g, (lvoid*)l, 16, 0, 0);
}

// ---------------------------------------------------------------------------
// Fused pre-kernel: blocks [0,1024) = pad_x, blocks [1024,1152) = prep_w.
// prep_w writes the FRAGMENT-CONTIGUOUS weight layout:
//   Wt[(((tap*4 + cb)*16 + otile)*64 + lane)*8 + j]
//   where o = otile*16 + (lane&15), c = cb*32 + (lane>>4)*8 + j.
// A conv wave loads fragment (tap,cb,otile) as one contiguous 1KB
// global_load_dwordx4 (lane l -> base + l*16B), no LDS, no swizzle.
__global__ void pad_prep(const float* __restrict__ x, __bf16* __restrict__ xpad,
                         const float* __restrict__ W, const float* __restrict__ lA,
                         const float* __restrict__ lB, __hip_bfloat16* __restrict__ Wt) {
    __shared__ float tile[128][66];
    const int t = threadIdx.x;

    if (blockIdx.x >= 1024) {
        // ---- prep_w: 128 blocks, each thread owns one (o,c), loops 9 taps
        const int idx = (blockIdx.x - 1024) * 256 + t;   // o*128 + c
        const int c = idx & 127;
        const int o = idx >> 7;
        const int fr    = o & 15;
        const int otile = o >> 4;
        const int cb    = c >> 5;
        const int kc    = (c >> 3) & 3;
        const int j     = c & 7;
        const int lane  = kc * 16 + fr;
        float lb[8];
#pragma unroll
        for (int r = 0; r < 8; ++r) lb[r] = lB[o * 8 + r];
#pragma unroll
        for (int tap = 0; tap < 9; ++tap) {
            float acc = W[(o * 128 + c) * 9 + tap];
            float s = 0.f;
#pragma unroll
            for (int r = 0; r < 8; ++r)
                s += lb[r] * lA[r * 1152 + c * 9 + tap];
            const size_t widx = (((size_t)(tap * 4 + cb) * 16 + otile) * 64 + lane) * 8 + j;
            Wt[widx] = __float2bfloat16(acc + 2.0f * s);
        }
        return;
    }

    // ---- pad_x: NCHW fp32 -> NHWC bf16 with +1 zero halo
    const int n = blockIdx.x >> 6;
    const int h = blockIdx.x & 63;
    const float* src = x + (size_t)n * 128 * 4096 + (size_t)h * 64;
#pragma unroll
    for (int i = 0; i < 8; ++i) {                      // 2048 float4 total
        int g  = i * 256 + t;
        int c  = g >> 4;
        int w4 = (g & 15) * 4;
        const float4 v = *reinterpret_cast<const float4*>(src + (size_t)c * 4096 + w4);
        const int wb = w4 ^ (((c >> 3) & 7) << 2);     // swizzle (bits 2..4)
        tile[c][wb + 0] = v.x; tile[c][wb + 1] = v.y;
        tile[c][wb + 2] = v.z; tile[c][wb + 3] = v.w;
    }
    __syncthreads();
    __bf16* dst = xpad + ((size_t)(n * 66 + h + 1) * 66 + 1) * 128;
#pragma unroll
    for (int i = 0; i < 4; ++i) {                      // 64w x 128c bf16 = 16KB
        int g  = i * 256 + t;
        int w  = g >> 4;
        int c0 = (g & 15) * 8;
        const int swr = ((c0 >> 3) & 7) << 2;          // (c0+j)>>3 == c0>>3, j<8
        bf16x8 v;
#pragma unroll
        for (int j = 0; j < 8; ++j) v[j] = (__bf16)tile[c0 + j][w ^ swr];
        *reinterpret_cast<bf16x8*>(dst + (size_t)w * 128 + c0) = v;
    }
    // halo: left/right pixel of this padded row
    bf16x8 z = {};
    __bf16* rowbase = xpad + (size_t)(n * 66 + h + 1) * 66 * 128;
    if (t < 32) {
        int ww = (t < 16) ? 0 : 65;
        int c0 = (t & 15) * 8;
        *reinterpret_cast<bf16x8*>(rowbase + (size_t)ww * 128 + c0) = z;
    }
    // top/bottom halo rows (full 66 px)
    if (h == 0 || h == 63) {
        __bf16* hrow = xpad + (size_t)(n * 66 + (h == 0 ? 0 : 65)) * 66 * 128;
        for (int i = t; i < 66 * 16; i += 256)
            *reinterpret_cast<bf16x8*>(hrow + (size_t)i * 8) = z;
    }
}

// ---------------------------------------------------------------------------
// Main kernel: m201-skeleton implicit-GEMM conv.
// grid 256 blocks x 512 thr. Block: n = blk>>4, output rows h0..h0+3 (256 pix).
// LDS slot layout (bf16 elems): slot s at s*16384; within slot row p (0..255,
// = block pixel) x 64 elems; 16B chunk q of row p at physical q^(p&7).
__global__ void __launch_bounds__(512, 2) conv_mfma(
    const __bf16* __restrict__ xpad, const __bf16* __restrict__ Wt,
    const float* __restrict__ bias, float* __restrict__ out) {
    __shared__ __align__(16) __bf16 lds[65536];        // 128 KiB = 4 x 32 KB

    const int tid  = threadIdx.x;
    const int wv   = tid >> 6;                         // 0..7
    const int lane = tid & 63;
    const int wm   = wv >> 2;                          // pix half: 0/1
    const int wn   = wv & 3;                           // o quarter: 0..3

    const int n  = blockIdx.x >> 4;                    // 16 tiles per image
    const int h0 = (blockIdx.x & 15) << 2;             // 4 output rows

    // ---- staging source pointers (one per quarter q = output row h0+q) ----
    // Per quarter-stage instr, wave wv covers rows [q*64 + wv*8, +8):
    // lane l -> row q*64 + wv*8 + (l>>3), chunk slot l&7 receives logical
    // chunk (l&7)^(row&7) = (l&7)^(l>>3)  (bases are multiples of 8).
    const __bf16* xq[4];
#pragma unroll
    for (int q = 0; q < 4; ++q)
        xq[q] = xpad + (((size_t)(n * 66 + h0 + q) * 66) + wv * 8 + (lane >> 3)) * 128
                     + (((lane & 7) ^ (lane >> 3)) << 3);

    // ---- fragment-read addressing ------------------------------------------
    // pixel frag (pi): rows wm*128 + pi*16 + (lane&15); k-chunk logical
    // = ks*4 + (lane>>4); physical = logical ^ (row&7), row&7 = lane&7.
    const int b_base = (wm * 128 + (lane & 15)) * 64;
    const int ph0 = (((lane >> 4) ^ (lane & 7)) << 3);
    const int ph1 = ph0 ^ 32;                          // ^4 in chunk = ^32 elems

    // ---- weight fragments: global->VGPR, fragment-contiguous layout --------
    const __bf16* wGbase = Wt + (size_t)(wn * 4) * 512 + lane * 8;

    f32x4 acc[8][4] = {};                              // [pix frag][o frag]
    f32x4 wA[8], wB[8];                                // [kb*4 + oi], ping-pong

#define WL(dst, ptr, imm)                                                      \
    asm volatile("global_load_dwordx4 %0, %1, off offset:" #imm                \
                 : "=&v"(dst) : "v"(ptr) : "memory")

#define WLOADS(WN, u_) do {                                                    \
        const int tap_ = (u_) >> 1, ch_ = (u_) & 1;                            \
        const __bf16* w0_ = wGbase + (size_t)(tap_ * 4 + ch_ * 2) * 8192;      \
        const __bf16* w1_ = w0_ + 8192;                                        \
        WL(WN[0], w0_, 0);    WL(WN[1], w0_, 1024);                            \
        WL(WN[2], w0_, 2048); WL(WN[3], w0_, 3072);                            \
        WL(WN[4], w1_, 0);    WL(WN[5], w1_, 1024);                            \
        WL(WN[6], w1_, 2048); WL(WN[7], w1_, 3072);                            \
    } while (0)

#define STAGEQ(u_, q_) do {                                                    \
        const int tap_ = (u_) >> 1, ch_ = (u_) & 1;                            \
        const int kh_ = (tap_ >= 6) ? 2 : (tap_ >= 3 ? 1 : 0);                 \
        const int kw_ = tap_ - kh_ * 3;                                        \
        const int off_ = (kh_ * 66 + kw_) * 128 + ch_ * 64;                    \
        load_lds16(xq[q_] + off_,                                              \
                   lds + ((u_) & 3) * 16384 + (q_) * 4096 + wv * 512);         \
    } while (0)

#define MF(P, KS, AI, OJ)                                                      \
    acc[AI][OJ] = __builtin_amdgcn_mfma_f32_16x16x32_bf16(                     \
        P, __builtin_bit_cast(bf16x8, WC[(KS) * 4 + (OJ)]), acc[AI][OJ], 0, 0, 0)

    // phase q_ of K-tile kt_: quadrant (qm=q_>>1: pix-half, qn=q_&1: o-half).
    // reads g0 + stage; SBAR; 8 MFMA; reads g1 (drain shadow); 8 MFMA.
#define PHASE(kt_, q_, WCp, DO_STAGE) do {                                     \
        const f32x4* const WC = (WCp);                                         \
        const __bf16* Pb_ = lds + ((kt_) & 3) * 16384 + b_base                 \
                          + ((q_) >> 1) * 4096;                                \
        bf16x8 p00 = *(const bf16x8*)(Pb_ + ph0);                              \
        bf16x8 p01 = *(const bf16x8*)(Pb_ + ph1);                              \
        bf16x8 p10 = *(const bf16x8*)(Pb_ + 1024 + ph0);                       \
        bf16x8 p11 = *(const bf16x8*)(Pb_ + 1024 + ph1);                       \
        if (DO_STAGE) STAGEQ((kt_) + 2, q_);                                   \
        __builtin_amdgcn_s_barrier();                                          \
        __builtin_amdgcn_s_setprio(1);                                         \
        MF(p00, 0, ((q_) >> 1) * 4 + 0, ((q_) & 1) * 2 + 0);                   \
        MF(p00, 0, ((q_) >> 1) * 4 + 0, ((q_) & 1) * 2 + 1);                   \
        MF(p01, 1, ((q_) >> 1) * 4 + 0, ((q_) & 1) * 2 + 0);                   \
        MF(p01, 1, ((q_) >> 1) * 4 + 0, ((q_) & 1) * 2 + 1);                   \
        MF(p10, 0, ((q_) >> 1) * 4 + 1, ((q_) & 1) * 2 + 0);                   \
        MF(p10, 0, ((q_) >> 1) * 4 + 1, ((q_) & 1) * 2 + 1);                   \
        MF(p11, 1, ((q_) >> 1) * 4 + 1, ((q_) & 1) * 2 + 0);                   \
        MF(p11, 1, ((q_) >> 1) * 4 + 1, ((q_) & 1) * 2 + 1);                   \
        __builtin_amdgcn_s_setprio(0);                                         \
        bf16x8 p20 = *(const bf16x8*)(Pb_ + 2048 + ph0);                       \
        bf16x8 p21 = *(const bf16x8*)(Pb_ + 2048 + ph1);                       \
        bf16x8 p30 = *(const bf16x8*)(Pb_ + 3072 + ph0);                       \
        bf16x8 p31 = *(const bf16x8*)(Pb_ + 3072 + ph1);                       \
        __builtin_amdgcn_s_setprio(1);                                         \
        MF(p20, 0, ((q_) >> 1) * 4 + 2, ((q_) & 1) * 2 + 0);                   \
        MF(p20, 0, ((q_) >> 1) * 4 + 2, ((q_) & 1) * 2 + 1);                   \
        MF(p21, 1, ((q_) >> 1) * 4 + 2, ((q_) & 1) * 2 + 0);                   \
        MF(p21, 1, ((q_) >> 1) * 4 + 2, ((q_) & 1) * 2 + 1);                   \
        MF(p30, 0, ((q_) >> 1) * 4 + 3, ((q_) & 1) * 2 + 0);                   \
        MF(p30, 0, ((q_) >> 1) * 4 + 3, ((q_) & 1) * 2 + 1);                   \
        MF(p31, 1, ((q_) >> 1) * 4 + 3, ((q_) & 1) * 2 + 0);                   \
        MF(p31, 1, ((q_) >> 1) * 4 + 3, ((q_) & 1) * 2 + 1);                   \
        __builtin_amdgcn_s_setprio(0);                                         \
    } while (0)

    // K-tile body: WLOADS(kt+1), 4 phases (stage kt+2), counted vmcnt + BAR.
    // vmcnt queue at wait: [4 sB(kt+1), 8 WL(kt+1), 4 sB(kt+2)] -> vmcnt(4)
    // retires sB(kt+1)+WL(kt+1), leaves sB(kt+2) IN FLIGHT (T4: never 0).
#define KTBODY(kt_, WCk, WN) do {                                              \
        WLOADS(WN, (kt_) + 1);                                                 \
        PHASE(kt_, 0, WCk, 1); PHASE(kt_, 1, WCk, 1);                          \
        PHASE(kt_, 2, WCk, 1); PHASE(kt_, 3, WCk, 1);                          \
        asm volatile("s_waitcnt vmcnt(4)" ::: "memory");                       \
        __builtin_amdgcn_sched_barrier(0);                                     \
        __builtin_amdgcn_s_barrier();                                          \
        __builtin_amdgcn_sched_barrier(0);                                     \
    } while (0)

    // prologue: weights kt0 -> wA; stage kt0+kt1 (slots 0,1).
    WLOADS(wA, 0);
    STAGEQ(0, 0); STAGEQ(0, 1); STAGEQ(0, 2); STAGEQ(0, 3);
    STAGEQ(1, 0); STAGEQ(1, 1); STAGEQ(1, 2); STAGEQ(1, 3);
    // queue: [8 WL(0), 4 sB(0), 4 sB(1)] -> vmcnt(4) retires WL(0)+sB(0)
    asm volatile("s_waitcnt vmcnt(4)" ::: "memory");
    __builtin_amdgcn_sched_barrier(0);
    __builtin_amdgcn_s_barrier();
    __builtin_amdgcn_sched_barrier(0);

    for (int ktt = 0; ktt < 8; ++ktt) {                // K-tiles 0..15
        KTBODY(2 * ktt,     wA, wB);
        KTBODY(2 * ktt + 1, wB, wA);
    }
    // kt = 16: compute wA, load wB(17), no stage (kt+2 = 18 doesn't exist)
    WLOADS(wB, 17);
    PHASE(16, 0, wA, 0); PHASE(16, 1, wA, 0);
    PHASE(16, 2, wA, 0); PHASE(16, 3, wA, 0);
    asm volatile("s_waitcnt vmcnt(0)" ::: "memory");   // drain WL(17)+sB(17)
    __builtin_amdgcn_sched_barrier(0);
    __builtin_amdgcn_s_barrier();
    __builtin_amdgcn_sched_barrier(0);
    // kt = 17: compute wB
    PHASE(17, 0, wB, 0); PHASE(17, 1, wB, 0);
    PHASE(17, 2, wB, 0); PHASE(17, 3, wB, 0);

#undef KTBODY
#undef PHASE
#undef MF
#undef STAGEQ
#undef WLOADS
#undef WL

    // epilogue (swapped D, R6-verified): D row=(lane>>4)*4+j = pixel,
    // col=lane&15 = o. Lane's 4 acc comps = 4 consecutive w -> dwordx4.
    const int col = lane & 15;
    const int q4  = (lane >> 4) << 2;
    float bo[4];
#pragma unroll
    for (int oj = 0; oj < 4; ++oj) bo[oj] = bias[wn * 64 + oj * 16 + col];
#pragma unroll
    for (int pi = 0; pi < 8; ++pi) {
        const int X  = pi * 16 + q4;                   // 0..124
        const int h  = h0 + wm * 2 + (X >> 6);
        const int w0 = X & 63;
#pragma unroll
        for (int oj = 0; oj < 4; ++oj) {
            const int o = wn * 64 + oj * 16 + col;
            f32x4 v;
#pragma unroll
            for (int j = 0; j < 4; ++j) v[j] = acc[pi][oj][j] + bo[oj];
            *reinterpret_cast<f32x4*>(out + (((size_t)n * 256 + o) * 64 + h) * 64 + w0) = v;
        }
    }
}

// ---------------------------------------------------------------------------
// Fallback (only if workspace too small): naive fp32, correct but slow.
__global__ void conv_naive(const float* __restrict__ x, const float* __restrict__ W,
                           const float* __restrict__ b, const float* __restrict__ lA,
                           const float* __restrict__ lB, float* __restrict__ out) {
    int idx = blockIdx.x * 256 + threadIdx.x;          // ((n*256+o)*64+h)*64+w
    int w = idx & 63, h = (idx >> 6) & 63, o = (idx >> 12) & 255, n = idx >> 20;
    float acc = b[o];
    float hr[8] = {0, 0, 0, 0, 0, 0, 0, 0};
    for (int c = 0; c < 128; ++c)
        for (int kh = 0; kh < 3; ++kh) {
            int hy = h + kh - 1;
            if (hy < 0 || hy > 63) continue;
            for (int kw = 0; kw < 3; ++kw) {
                int wx = w + kw - 1;
                if (wx < 0 || wx > 63) continue;
                float xv = x[((n * 128 + c) * 64 + hy) * 64 + wx];
                int ka = c * 9 + kh * 3 + kw;
                acc += W[(o * 128 + c) * 9 + kh * 3 + kw] * xv;
#pragma unroll
                for (int r = 0; r < 8; ++r) hr[r] += lA[r * 1152 + ka] * xv;
            }
        }
    float ls = 0.f;
#pragma unroll
    for (int r = 0; r < 8; ++r) ls += lB[o * 8 + r] * hr[r];
    out[idx] = acc + 2.0f * ls;
}

// ---------------------------------------------------------------------------
extern "C" void kernel_launch(void* const* d_in, const int* in_sizes, int n_in,
                              void* d_out, int out_size, void* d_ws, size_t ws_size,
                              hipStream_t stream) {
    const float* x  = (const float*)d_in[0];
    const float* W  = (const float*)d_in[1];
    const float* b  = (const float*)d_in[2];
    const float* lA = (const float*)d_in[3];
    const float* lB = (const float*)d_in[4];
    float* out = (float*)d_out;

    if (ws_size < WS_NEED) {
        conv_naive<<<out_size / 256, 256, 0, stream>>>(x, W, b, lA, lB, out);
        return;
    }

    __bf16* xpad = (__bf16*)d_ws;
    __hip_bfloat16* Wt = (__hip_bfloat16*)((char*)d_ws + XPAD_BYTES);

    pad_prep<<<1024 + 128, 256, 0, stream>>>(x, xpad, W, lA, lB, Wt);
    conv_mfma<<<256, 512, 0, stream>>>(xpad, (const __bf16*)Wt, b, out);
}

// Round 10
// 131.235 us; speedup vs baseline: 1.0766x; 1.0766x over previous
//
#include <hip/hip_runtime.h>
#include <hip/hip_bf16.h>

// Conv2dWithLoRA: out = conv3x3(x, W_eff) + b, where W_eff = W + 2.0 * B@A.
// LoRA folded into weights -> single implicit-GEMM conv, bf16 MFMA, fp32 accum.
// M = 16*64*64 = 65536 pixels, N = 256 outs, K = 1152 (18 chunks of 64).
// History: R3 (256^2 tile, depth-1 dbuf, 2 bar/chunk) = BEST: 44.8-48.0 us.
//   R4-R11 (quad-buffer, phase-split, weights-in-VGPR, 2-blocks/CU, m201
//   8-phase port) all null or regressions at 26-32% MfmaUtil. Schedule
//   dimension exhausted; m201's gain did not survive blind porting (matches
//   guide m232's open quadrant).
// R12 (this round): RESTORE R3 exactly + ROLL the K-loop.
//   - every prior kernel fully unrolled 18 chunks (10-30 KB straight-line
//     code; R11's ~30 KB exceeds 32 KB L1I). m97/m201/HK all use rolled
//     loops with I$-resident bodies. Rolled body ~800 B.
//   - scalar epilogue restored (64B-coalesced stores: WRITE_SIZE 65.5 MB
//     clean vs 78-81 MB for the 16B-segment swapped epilogue).
//   - prep_w back to tap-major layout Wt[tap][o][c] (R3 staging path).

#define CIN   128
#define COUT  256
#define NBAT  16
#define HPAD  66
#define WPAD  66

typedef __bf16 bf16x8 __attribute__((ext_vector_type(8)));
typedef float f32x4 __attribute__((ext_vector_type(4)));

#define XPAD_ELEMS ((size_t)NBAT * HPAD * WPAD * CIN)   // 8,921,088
#define XPAD_BYTES (XPAD_ELEMS * 2)                      // 17,842,176
#define WT_ELEMS   ((size_t)9 * COUT * CIN)              // 294,912
#define WS_NEED    (XPAD_BYTES + WT_ELEMS * 2)

typedef __attribute__((address_space(1))) void gvoid;
typedef __attribute__((address_space(3))) void lvoid;

__device__ __forceinline__ void load_lds16(const void* g, void* l) {
    // async global->LDS, 16B per lane; LDS dest = wave-uniform base + lane*16
    __builtin_amdgcn_global_load_lds((gvoid*)g, (lvoid*)l, 16, 0, 0);
}

// ---------------------------------------------------------------------------
// Fused pre-kernel: blocks [0,1024) = pad_x, blocks [1024,1152) = prep_w.
// prep_w: W_eff = W + 2*B@A, cast bf16, layout Wt[tap][o][c] (c contig).
__global__ void pad_prep(const float* __restrict__ x, __bf16* __restrict__ xpad,
                         const float* __restrict__ W, const float* __restrict__ lA,
                         const float* __restrict__ lB, __hip_bfloat16* __restrict__ Wt) {
    __shared__ float tile[128][66];
    const int t = threadIdx.x;

    if (blockIdx.x >= 1024) {
        // ---- prep_w: 128 blocks, each thread owns one (o,c), loops 9 taps
        const int idx = (blockIdx.x - 1024) * 256 + t;   // o*128 + c
        const int c = idx & 127;
        const int o = idx >> 7;
        float lb[8];
#pragma unroll
        for (int r = 0; r < 8; ++r) lb[r] = lB[o * 8 + r];
#pragma unroll
        for (int tap = 0; tap < 9; ++tap) {
            float acc = W[(o * 128 + c) * 9 + tap];
            float s = 0.f;
#pragma unroll
            for (int r = 0; r < 8; ++r)
                s += lb[r] * lA[r * 1152 + c * 9 + tap];
            Wt[tap * 32768 + idx] = __float2bfloat16(acc + 2.0f * s);
        }
        return;
    }

    // ---- pad_x: NCHW fp32 -> NHWC bf16 with +1 zero halo
    const int n = blockIdx.x >> 6;
    const int h = blockIdx.x & 63;
    const float* src = x + (size_t)n * 128 * 4096 + (size_t)h * 64;
#pragma unroll
    for (int i = 0; i < 8; ++i) {                      // 2048 float4 total
        int g  = i * 256 + t;
        int c  = g >> 4;
        int w4 = (g & 15) * 4;
        const float4 v = *reinterpret_cast<const float4*>(src + (size_t)c * 4096 + w4);
        const int wb = w4 ^ (((c >> 3) & 7) << 2);     // swizzle (bits 2..4)
        tile[c][wb + 0] = v.x; tile[c][wb + 1] = v.y;
        tile[c][wb + 2] = v.z; tile[c][wb + 3] = v.w;
    }
    __syncthreads();
    __bf16* dst = xpad + ((size_t)(n * 66 + h + 1) * 66 + 1) * 128;
#pragma unroll
    for (int i = 0; i < 4; ++i) {                      // 64w x 128c bf16 = 16KB
        int g  = i * 256 + t;
        int w  = g >> 4;
        int c0 = (g & 15) * 8;
        const int swr = ((c0 >> 3) & 7) << 2;          // (c0+j)>>3 == c0>>3, j<8
        bf16x8 v;
#pragma unroll
        for (int j = 0; j < 8; ++j) v[j] = (__bf16)tile[c0 + j][w ^ swr];
        *reinterpret_cast<bf16x8*>(dst + (size_t)w * 128 + c0) = v;
    }
    // halo: left/right pixel of this padded row
    bf16x8 z = {};
    __bf16* rowbase = xpad + (size_t)(n * 66 + h + 1) * 66 * 128;
    if (t < 32) {
        int ww = (t < 16) ? 0 : 65;
        int c0 = (t & 15) * 8;
        *reinterpret_cast<bf16x8*>(rowbase + (size_t)ww * 128 + c0) = z;
    }
    // top/bottom halo rows (full 66 px)
    if (h == 0 || h == 63) {
        __bf16* hrow = xpad + (size_t)(n * 66 + (h == 0 ? 0 : 65)) * 66 * 128;
        for (int i = t; i < 66 * 16; i += 256)
            *reinterpret_cast<bf16x8*>(hrow + (size_t)i * 8) = z;
    }
}

// ---------------------------------------------------------------------------
// Main kernel: implicit-GEMM conv, R3 structure (best measured), rolled loop.
// Tile 256(o) x 256(pix), BK=64, 8 waves (wo half x wpix quarter), per-wave
// 128o x 64pix, acc[8][4]. LDS 128 KiB: A bufs at {0,16384}, B at
// 32768+{0,16384} (elems). Depth-1 double buffer:
//   iter t: wait vmcnt(0)+lgkmcnt(0) (stage t issued last iter -> cheap);
//   s_barrier; STAGE(t+1) into buf (t+1)&1; COMPUTE(t) from buf t&1.
// Stage never targets the buffer read this iter; reads of its target buffer
// finished before the barrier (lgkm fence + program order) -> race-free.
// XOR swizzle (verified R3, 0 conflicts): physical 16B chunk of logical
// (row, q) is q^(row&7); inverse pre-applied on per-lane GLOBAL address
// (swz), LDS dest stays linear (global_load_lds requirement, rule #21).
__global__ void __launch_bounds__(512, 2) conv_mfma(
    const __bf16* __restrict__ xpad, const __bf16* __restrict__ Wt,
    const float* __restrict__ bias, float* __restrict__ out) {
    __shared__ __align__(16) __bf16 lds[65536];        // 128 KiB

    const int tid  = threadIdx.x;
    const int wv   = tid >> 6;                         // 0..7
    const int lane = tid & 63;

    const int n  = blockIdx.x >> 4;                    // 16 tiles per image
    const int h0 = (blockIdx.x & 15) << 2;             // 4 output rows per tile

    // per-lane swizzled source offset (elements), shared by A and B staging:
    // row-within-8 = lane>>3, logical chunk = (lane&7) ^ (lane>>3)
    const int swz = ((lane >> 3) << 7) + ((((lane & 7) ^ (lane >> 3)) & 7) << 3);

    const __bf16* aG[4];
    const __bf16* bG[4];
#pragma unroll
    for (int j = 0; j < 4; ++j) {
        const int r0 = j * 64 + wv * 8;                // rows covered: 8 per instr
        aG[j] = Wt + (size_t)r0 * 128 + swz;
        bG[j] = xpad + (((size_t)(n * 66 + h0 + (r0 >> 6)) * 66 + (r0 & 63)) * 128) + swz;
    }
    // NOTE: r0 here = j*64 + wv*8 spans 0..248 in steps of 8 across (j,wv),
    // covering all 256 rows exactly once; LDS dest below matches this order.

    const int wo   = (wv >> 2) << 7;                   // o offset: 0 / 128
    const int wpix = (wv & 3) << 6;                    // pix offset: 0/64/128/192
    const int a_rd = (wo + (lane & 15)) << 6;          // LDS row = 64 elems
    const int b_rd = (wpix + (lane & 15)) << 6;
    int qo[2];
#pragma unroll
    for (int s = 0; s < 2; ++s)
        qo[s] = ((((lane >> 4) + s * 4) ^ (lane & 7)) << 3);

    f32x4 acc[8][4] = {};

    // ---- STAGE(u): 4 A-instrs + 4 B-instrs, 1 KB each --------------------
#define STAGE(u_) do {                                                         \
        const int tap_ = (u_) >> 1, cb_ = (u_) & 1;                            \
        const int kh_ = (tap_ >= 6) ? 2 : (tap_ >= 3 ? 1 : 0);                 \
        const int kw_ = tap_ - kh_ * 3;                                        \
        const int ao_ = tap_ * 32768 + cb_ * 64;                               \
        const int bo_ = (kh_ * 66 + kw_) * 128 + cb_ * 64;                     \
        __bf16* Ad_ = lds + ((u_) & 1) * 16384;                                \
        __bf16* Bd_ = lds + 32768 + ((u_) & 1) * 16384;                        \
        _Pragma("unroll")                                                      \
        for (int j = 0; j < 4; ++j) {                                          \
            load_lds16(aG[j] + ao_, Ad_ + (j * 64 + wv * 8) * 64);             \
            load_lds16(bG[j] + bo_, Bd_ + (j * 64 + wv * 8) * 64);             \
        }                                                                      \
    } while (0)

#define COMPUTE(t_) do {                                                       \
        const __bf16* Ab = lds + ((t_) & 1) * 16384 + a_rd;                    \
        const __bf16* Bb = lds + 32768 + ((t_) & 1) * 16384 + b_rd;            \
        _Pragma("unroll")                                                      \
        for (int s = 0; s < 2; ++s) {                                          \
            bf16x8 af[8], bfr[4];                                              \
            _Pragma("unroll")                                                  \
            for (int ni = 0; ni < 4; ++ni)                                     \
                bfr[ni] = *reinterpret_cast<const bf16x8*>(Bb + (ni << 10) + qo[s]); \
            _Pragma("unroll")                                                  \
            for (int mi = 0; mi < 8; ++mi)                                     \
                af[mi] = *reinterpret_cast<const bf16x8*>(Ab + (mi << 10) + qo[s]); \
            __builtin_amdgcn_s_setprio(1);                                     \
            _Pragma("unroll")                                                  \
            for (int mi = 0; mi < 8; ++mi)                                     \
                _Pragma("unroll")                                              \
                for (int ni = 0; ni < 4; ++ni)                                 \
                    acc[mi][ni] = __builtin_amdgcn_mfma_f32_16x16x32_bf16(     \
                        af[mi], bfr[ni], acc[mi][ni], 0, 0, 0);                \
            __builtin_amdgcn_s_setprio(0);                                     \
        }                                                                      \
    } while (0)

    // prologue: stage chunk 0 -> buf 0
    STAGE(0);

    // ROLLED main loop (body ~800 B, I$-resident; all prior rounds unrolled)
    for (int t = 0; t < 17; ++t) {
        asm volatile("s_waitcnt vmcnt(0) lgkmcnt(0)" ::: "memory");
        __builtin_amdgcn_sched_barrier(0);
        __builtin_amdgcn_s_barrier();
        __builtin_amdgcn_sched_barrier(0);
        STAGE(t + 1);
        COMPUTE(t);
    }
    // tail: chunk 17 (no further stage)
    asm volatile("s_waitcnt vmcnt(0) lgkmcnt(0)" ::: "memory");
    __builtin_amdgcn_sched_barrier(0);
    __builtin_amdgcn_s_barrier();
    __builtin_amdgcn_sched_barrier(0);
    COMPUTE(17);

#undef COMPUTE
#undef STAGE

    // epilogue (R3-verified, 64B-coalesced scalar stores):
    // D row=(lane>>4)*4+j (o), col=lane&15 (pix); + bias
    const int col  = lane & 15;
    const int orow = (lane >> 4) << 2;
    const int h    = h0 + (wpix >> 6);                 // wave's output row
#pragma unroll
    for (int mi = 0; mi < 8; ++mi) {
        const int obm = wo + mi * 16 + orow;
#pragma unroll
        for (int j = 0; j < 4; ++j) {
            const int o = obm + j;
            const float bj = bias[o];
            float* orow_ptr = out + (((size_t)n * 256 + o) * 64 + h) * 64;
#pragma unroll
            for (int ni = 0; ni < 4; ++ni)
                orow_ptr[ni * 16 + col] = acc[mi][ni][j] + bj;
        }
    }
}

// ---------------------------------------------------------------------------
// Fallback (only if workspace too small): naive fp32, correct but slow.
__global__ void conv_naive(const float* __restrict__ x, const float* __restrict__ W,
                           const float* __restrict__ b, const float* __restrict__ lA,
                           const float* __restrict__ lB, float* __restrict__ out) {
    int idx = blockIdx.x * 256 + threadIdx.x;          // ((n*256+o)*64+h)*64+w
    int w = idx & 63, h = (idx >> 6) & 63, o = (idx >> 12) & 255, n = idx >> 20;
    float acc = b[o];
    float hr[8] = {0, 0, 0, 0, 0, 0, 0, 0};
    for (int c = 0; c < 128; ++c)
        for (int kh = 0; kh < 3; ++kh) {
            int hy = h + kh - 1;
            if (hy < 0 || hy > 63) continue;
            for (int kw = 0; kw < 3; ++kw) {
                int wx = w + kw - 1;
                if (wx < 0 || wx > 63) continue;
                float xv = x[((n * 128 + c) * 64 + hy) * 64 + wx];
                int ka = c * 9 + kh * 3 + kw;
                acc += W[(o * 128 + c) * 9 + kh * 3 + kw] * xv;
#pragma unroll
                for (int r = 0; r < 8; ++r) hr[r] += lA[r * 1152 + ka] * xv;
            }
        }
    float ls = 0.f;
#pragma unroll
    for (int r = 0; r < 8; ++r) ls += lB[o * 8 + r] * hr[r];
    out[idx] = acc + 2.0f * ls;
}

// ---------------------------------------------------------------------------
extern "C" void kernel_launch(void* const* d_in, const int* in_sizes, int n_in,
                              void* d_out, int out_size, void* d_ws, size_t ws_size,
                              hipStream_t stream) {
    const float* x  = (const float*)d_in[0];
    const float* W  = (const float*)d_in[1];
    const float* b  = (const float*)d_in[2];
    const float* lA = (const float*)d_in[3];
    const float* lB = (const float*)d_in[4];
    float* out = (float*)d_out;

    if (ws_size < WS_NEED) {
        conv_naive<<<out_size / 256, 256, 0, stream>>>(x, W, b, lA, lB, out);
        return;
    }

    __bf16* xpad = (__bf16*)d_ws;
    __hip_bfloat16* Wt = (__hip_bfloat16*)((char*)d_ws + XPAD_BYTES);

    pad_prep<<<1024 + 128, 256, 0, stream>>>(x, xpad, W, lA, lB, Wt);
    conv_mfma<<<256, 512, 0, stream>>>(xpad, (const __bf16*)Wt, b, out);
}